// Round 5
// baseline (462.830 us; speedup 1.0000x reference)
//
#include <hip/hip_runtime.h>
#include <math.h>

#define NBROWS 262144

typedef float v2f __attribute__((ext_vector_type(2)));
struct alignas(16) F4 { v2f lo, hi; };

__device__ __forceinline__ v2f sp(float x){ v2f r; r.x = x; r.y = x; return r; }

// ---------------- packed d_ws layout (floats) ----------------
// P1 [0,1152):     36 pairs (u<=v, u-major) x 32: [Sss w0..15][Svv0 w0..15]
// C1 [1152,2176):  (vv*8+u)*16 + w   : c1/sqrt3*(w_sv[u,vv,w]+w_vs[vv,u,w])
// A1 [2176,2624):  28 pairs (u<v) x 16
// P2 [2624,4800):  136 pairs (u<=v) x 16: [Sss w0..7][Svv0 w0..7]
// C2 [4800,6848):  (vv*16+u)*8 + w
// A2 [6848,7808):  120 pairs (u<v) x 8
#define WS_TOT 7808

__device__ void pair_le(int p, int M, int& u, int& v) {  // u<=v, u-major
    u = 0; int cnt = M;
    while (p >= cnt) { p -= cnt; ++u; cnt = M - u; }
    v = u + p;
}
__device__ void pair_lt(int p, int M, int& u, int& v) {  // u<v, u-major
    u = 0; int cnt = M - 1;
    while (p >= cnt) { p -= cnt; ++u; cnt = M - 1 - u; }
    v = u + 1 + p;
}

__global__ __launch_bounds__(256) void prep_kernel(
    const float* __restrict__ w1_ss, const float* __restrict__ w1_vv0,
    const float* __restrict__ w1_sv, const float* __restrict__ w1_vs,
    const float* __restrict__ w1_vv1,
    const float* __restrict__ w2_ss, const float* __restrict__ w2_vv0,
    const float* __restrict__ w2_sv, const float* __restrict__ w2_vs,
    const float* __restrict__ w2_vv1,
    float* __restrict__ ws)
{
    const float inv3 = 0.5773502691896258f;
    const float inv6 = 0.4082482904638631f;
    int i = blockIdx.x * 256 + threadIdx.x;
    if (i >= WS_TOT) return;
    float val = 0.f;
    if (i < 1152) {                       // P1
        int p = i >> 5, r = i & 31;
        int which = r >> 4, w = r & 15;
        int u, v; pair_le(p, 8, u, v);
        const float c0 = 0.08838834764831845f;   // 1/sqrt(64+64)
        const float* src = which ? w1_vv0 : w1_ss;
        float cc = which ? c0 * inv3 : c0;
        val = (u == v) ? cc * src[(u*8+v)*16+w]
                       : cc * (src[(u*8+v)*16+w] + src[(v*8+u)*16+w]);
    } else if (i < 2176) {                // C1
        int r = i - 1152; int vv = r >> 7, rem = r & 127, u = rem >> 4, w = rem & 15;
        val = (0.125f * inv3) * (w1_sv[(u*8+vv)*16+w] + w1_vs[(vv*8+u)*16+w]);
    } else if (i < 2624) {                // A1
        int r = i - 2176; int p = r >> 4, w = r & 15;
        int u, v; pair_lt(p, 8, u, v);
        val = (0.125f * inv6) * (w1_vv1[(u*8+v)*16+w] - w1_vv1[(v*8+u)*16+w]);
    } else if (i < 4800) {                // P2
        int r = i - 2624; int p = r >> 4, rr = r & 15, which = rr >> 3, w = rr & 7;
        int u, v; pair_le(p, 16, u, v);
        const float c0 = 0.04419417382415922f;   // 1/sqrt(256+256)
        const float* src = which ? w2_vv0 : w2_ss;
        float cc = which ? c0 * inv3 : c0;
        val = (u == v) ? cc * src[(u*16+v)*8+w]
                       : cc * (src[(u*16+v)*8+w] + src[(v*16+u)*8+w]);
    } else if (i < 6848) {                // C2
        int r = i - 4800; int vv = r >> 7, rem = r & 127, u = rem >> 3, w = rem & 7;
        val = (0.0625f * inv3) * (w2_sv[(u*16+vv)*8+w] + w2_vs[(vv*16+u)*8+w]);
    } else {                              // A2
        int r = i - 6848; int p = r >> 3, w = r & 7;
        int u, v; pair_lt(p, 16, u, v);
        val = (0.0625f * inv6) * (w2_vv1[(u*16+v)*8+w] - w2_vv1[(v*16+u)*8+w]);
    }
    ws[i] = val;
}

// ---------------- layer 1: 8 -> 16, chunk of 8 outputs (4 v2f) ----------------
template<int W0>
__device__ __forceinline__ void l1_chunk(const float* Wl,
    const float (&s)[8], const float (&v)[8][3],
    v2f (&ys2)[8], v2f (&ox)[8], v2f (&oy)[8], v2f (&oz)[8])
{
    const int J0 = W0 / 2;
#pragma unroll
    for (int j = 0; j < 4; ++j) { ys2[J0+j]=sp(0.f); ox[J0+j]=sp(0.f); oy[J0+j]=sp(0.f); oz[J0+j]=sp(0.f); }
    {   // symmetric ss+vv0
        int p = 0;
#pragma unroll
        for (int u = 0; u < 8; ++u)
#pragma unroll
        for (int vv = u; vv < 8; ++vv) {
            float pp = s[u] * s[vv];
            float dd = v[u][0]*v[vv][0] + v[u][1]*v[vv][1] + v[u][2]*v[vv][2];
            const F4* qa = reinterpret_cast<const F4*>(Wl + p*32 + W0);
            const F4* qb = reinterpret_cast<const F4*>(Wl + p*32 + 16 + W0);
            F4 a0 = qa[0], a1 = qa[1], b0 = qb[0], b1 = qb[1];
            v2f vp = sp(pp), vd = sp(dd);
            ys2[J0+0] += vp*a0.lo + vd*b0.lo;
            ys2[J0+1] += vp*a0.hi + vd*b0.hi;
            ys2[J0+2] += vp*a1.lo + vd*b1.lo;
            ys2[J0+3] += vp*a1.hi + vd*b1.hi;
            ++p;
        }
    }
    // combined sv+vs
#pragma unroll
    for (int vv = 0; vv < 8; ++vv) {
        v2f tw0 = sp(0.f), tw1 = sp(0.f), tw2 = sp(0.f), tw3 = sp(0.f);
#pragma unroll
        for (int u = 0; u < 8; ++u) {
            const F4* qc = reinterpret_cast<const F4*>(Wl + 1152 + (vv*8+u)*16 + W0);
            F4 c0 = qc[0], c1 = qc[1];
            v2f su = sp(s[u]);
            tw0 += su*c0.lo; tw1 += su*c0.hi; tw2 += su*c1.lo; tw3 += su*c1.hi;
        }
        v2f vx = sp(v[vv][0]), vy = sp(v[vv][1]), vz = sp(v[vv][2]);
        ox[J0+0] += tw0*vx; ox[J0+1] += tw1*vx; ox[J0+2] += tw2*vx; ox[J0+3] += tw3*vx;
        oy[J0+0] += tw0*vy; oy[J0+1] += tw1*vy; oy[J0+2] += tw2*vy; oy[J0+3] += tw3*vy;
        oz[J0+0] += tw0*vz; oz[J0+1] += tw1*vz; oz[J0+2] += tw2*vz; oz[J0+3] += tw3*vz;
    }
    {   // antisymmetric cross
        int p = 0;
#pragma unroll
        for (int u = 0; u < 8; ++u)
#pragma unroll
        for (int vv = u + 1; vv < 8; ++vv) {
            float cx = v[u][1]*v[vv][2] - v[u][2]*v[vv][1];
            float cy = v[u][2]*v[vv][0] - v[u][0]*v[vv][2];
            float cz = v[u][0]*v[vv][1] - v[u][1]*v[vv][0];
            const F4* qa = reinterpret_cast<const F4*>(Wl + 2176 + p*16 + W0);
            F4 a0 = qa[0], a1 = qa[1];
            v2f vcx = sp(cx), vcy = sp(cy), vcz = sp(cz);
            ox[J0+0] += vcx*a0.lo; ox[J0+1] += vcx*a0.hi; ox[J0+2] += vcx*a1.lo; ox[J0+3] += vcx*a1.hi;
            oy[J0+0] += vcy*a0.lo; oy[J0+1] += vcy*a0.hi; oy[J0+2] += vcy*a1.lo; oy[J0+3] += vcy*a1.hi;
            oz[J0+0] += vcz*a0.lo; oz[J0+1] += vcz*a0.hi; oz[J0+2] += vcz*a1.lo; oz[J0+3] += vcz*a1.hi;
            ++p;
        }
    }
}

// ---------------- layer 2: 16 -> 8, chunk of 4 outputs (2 v2f) ----------------
template<int W0>
__device__ __forceinline__ void l2_chunk(const float* Wl,
    const float (&s)[16], const float (&v)[16][3],
    v2f (&zs2)[4], v2f (&zx)[4], v2f (&zy)[4], v2f (&zz)[4])
{
    const int J0 = W0 / 2;
#pragma unroll
    for (int j = 0; j < 2; ++j) { zs2[J0+j]=sp(0.f); zx[J0+j]=sp(0.f); zy[J0+j]=sp(0.f); zz[J0+j]=sp(0.f); }
    {   // symmetric
        int p = 0;
#pragma unroll
        for (int u = 0; u < 16; ++u)
#pragma unroll
        for (int vv = u; vv < 16; ++vv) {
            float pp = s[u] * s[vv];
            float dd = v[u][0]*v[vv][0] + v[u][1]*v[vv][1] + v[u][2]*v[vv][2];
            const F4* qa = reinterpret_cast<const F4*>(Wl + 2624 + p*16 + W0);
            const F4* qb = reinterpret_cast<const F4*>(Wl + 2624 + p*16 + 8 + W0);
            F4 a0 = qa[0]; F4 b0 = qb[0];
            v2f vp = sp(pp), vd = sp(dd);
            zs2[J0+0] += vp*a0.lo + vd*b0.lo;
            zs2[J0+1] += vp*a0.hi + vd*b0.hi;
            ++p;
        }
    }
#pragma unroll
    for (int vv = 0; vv < 16; ++vv) {
        v2f tw0 = sp(0.f), tw1 = sp(0.f);
#pragma unroll
        for (int u = 0; u < 16; ++u) {
            const F4* qc = reinterpret_cast<const F4*>(Wl + 4800 + (vv*16+u)*8 + W0);
            F4 c0 = qc[0];
            v2f su = sp(s[u]);
            tw0 += su*c0.lo; tw1 += su*c0.hi;
        }
        v2f vx = sp(v[vv][0]), vy = sp(v[vv][1]), vz = sp(v[vv][2]);
        zx[J0+0] += tw0*vx; zx[J0+1] += tw1*vx;
        zy[J0+0] += tw0*vy; zy[J0+1] += tw1*vy;
        zz[J0+0] += tw0*vz; zz[J0+1] += tw1*vz;
    }
    {   // cross
        int p = 0;
#pragma unroll
        for (int u = 0; u < 16; ++u)
#pragma unroll
        for (int vv = u + 1; vv < 16; ++vv) {
            float cx = v[u][1]*v[vv][2] - v[u][2]*v[vv][1];
            float cy = v[u][2]*v[vv][0] - v[u][0]*v[vv][2];
            float cz = v[u][0]*v[vv][1] - v[u][1]*v[vv][0];
            const F4* qa = reinterpret_cast<const F4*>(Wl + 6848 + p*8 + W0);
            F4 a0 = qa[0];
            zx[J0+0] += sp(cx)*a0.lo; zx[J0+1] += sp(cx)*a0.hi;
            zy[J0+0] += sp(cy)*a0.lo; zy[J0+1] += sp(cy)*a0.hi;
            zz[J0+0] += sp(cz)*a0.lo; zz[J0+1] += sp(cz)*a0.hi;
            ++p;
        }
    }
}

__device__ __forceinline__ void si_norm16_v(v2f (&ys2)[8], v2f (&ox)[8], v2f (&oy)[8], v2f (&oz)[8])
{
    v2f a = sp(0.f);
#pragma unroll
    for (int j = 0; j < 8; ++j) a += ys2[j];
    float m = (a.x + a.y) * (1.f/16);
    v2f vr = sp(0.f);
#pragma unroll
    for (int j = 0; j < 8; ++j) { v2f d = ys2[j] - sp(m); vr += d*d; }
    float inv = 1.f / (sqrtf((vr.x+vr.y) * (1.f/15)) + 1e-9f);
#pragma unroll
    for (int j = 0; j < 8; ++j) ys2[j] *= sp(inv);

    float n1[16]; float sum = 0.f;
#pragma unroll
    for (int j = 0; j < 8; ++j) {
        v2f nn = ox[j]*ox[j] + oy[j]*oy[j] + oz[j]*oz[j];
        n1[2*j]   = sqrtf(nn.x + 1e-9f);
        n1[2*j+1] = sqrtf(nn.y + 1e-9f);
        sum += n1[2*j] + n1[2*j+1];
    }
    float mn = sum * (1.f/16);
    float var = 0.f;
#pragma unroll
    for (int i = 0; i < 16; ++i) { float d = n1[i] - mn; var += d*d; }
    float invv = 1.f / (sqrtf(var * (1.f/15)) + 1e-9f);
    v2f vi = sp(invv);
#pragma unroll
    for (int j = 0; j < 8; ++j) { ox[j] *= vi; oy[j] *= vi; oz[j] *= vi; }
}

__device__ __forceinline__ void tv_norm16_v(v2f (&ys2)[8], v2f (&ox)[8], v2f (&oy)[8], v2f (&oz)[8])
{
    v2f ssum = sp(0.f);
#pragma unroll
    for (int j = 0; j < 8; ++j) ssum += ys2[j]*ys2[j];
    float inv = 1.f / sqrtf(ssum.x + ssum.y + 1e-6f);
#pragma unroll
    for (int j = 0; j < 8; ++j) ys2[j] *= sp(inv);

    v2f sx = sp(0.f), sy = sp(0.f), sz = sp(0.f);
#pragma unroll
    for (int j = 0; j < 8; ++j) { sx += ox[j]*ox[j]; sy += oy[j]*oy[j]; sz += oz[j]*oz[j]; }
    float nm = (sqrtf(sx.x+sx.y+1e-6f) + sqrtf(sy.x+sy.y+1e-6f) + sqrtf(sz.x+sz.y+1e-6f)) * (1.f/3.f);
    float invv = 1.f / (nm + 1e-6f);
#pragma unroll
    for (int j = 0; j < 8; ++j) { ox[j] *= sp(invv); oy[j] *= sp(invv); oz[j] *= sp(invv); }
}

__device__ __forceinline__ void si_norm8_v(v2f (&zs2)[4], v2f (&zx)[4], v2f (&zy)[4], v2f (&zz)[4])
{
    v2f a = sp(0.f);
#pragma unroll
    for (int j = 0; j < 4; ++j) a += zs2[j];
    float m = (a.x + a.y) * (1.f/8);
    v2f vr = sp(0.f);
#pragma unroll
    for (int j = 0; j < 4; ++j) { v2f d = zs2[j] - sp(m); vr += d*d; }
    float inv = 1.f / (sqrtf((vr.x+vr.y) * (1.f/7)) + 1e-9f);
#pragma unroll
    for (int j = 0; j < 4; ++j) zs2[j] *= sp(inv);

    float n1[8]; float sum = 0.f;
#pragma unroll
    for (int j = 0; j < 4; ++j) {
        v2f nn = zx[j]*zx[j] + zy[j]*zy[j] + zz[j]*zz[j];
        n1[2*j]   = sqrtf(nn.x + 1e-9f);
        n1[2*j+1] = sqrtf(nn.y + 1e-9f);
        sum += n1[2*j] + n1[2*j+1];
    }
    float mn = sum * (1.f/8);
    float var = 0.f;
#pragma unroll
    for (int i = 0; i < 8; ++i) { float d = n1[i] - mn; var += d*d; }
    float invv = 1.f / (sqrtf(var * (1.f/7)) + 1e-9f);
    v2f vi = sp(invv);
#pragma unroll
    for (int j = 0; j < 4; ++j) { zx[j] *= vi; zy[j] *= vi; zz[j] *= vi; }
}

__device__ __forceinline__ float fast_tanh(float x) {
    return 1.f - 2.f / (__expf(2.f * x) + 1.f);
}

// __launch_bounds__(256) only — no min-waves clause (R2: a waves floor demoted
// arrays to scratch). Chunked v2f accumulation + b128 broadcast weight reads.
__global__ __launch_bounds__(256) void DoubleLayer_main_kernel(
    const float* __restrict__ x,
    const float* __restrict__ ws,
    float* __restrict__ out)
{
    __shared__ float Wl[WS_TOT];

    int row = blockIdx.x * 256 + threadIdx.x;
    const float4* xr = reinterpret_cast<const float4*>(x + (size_t)row * 32);
    float4 q0 = xr[0], q1 = xr[1], q2 = xr[2], q3 = xr[3];
    float4 q4 = xr[4], q5 = xr[5], q6 = xr[6], q7 = xr[7];

    // stage packed weights: 1952 float4
#pragma unroll
    for (int i = 0; i < 8; ++i) {
        int idx = threadIdx.x + i * 256;
        if (idx < WS_TOT/4)
            reinterpret_cast<float4*>(Wl)[idx] = reinterpret_cast<const float4*>(ws)[idx];
    }
    __syncthreads();

    float s1[8];
    s1[0] = fast_tanh(q0.x); s1[1] = fast_tanh(q0.y); s1[2] = fast_tanh(q0.z); s1[3] = fast_tanh(q0.w);
    s1[4] = fast_tanh(q1.x); s1[5] = fast_tanh(q1.y); s1[6] = fast_tanh(q1.z); s1[7] = fast_tanh(q1.w);
    float v1[8][3];
    v1[0][0]=q2.x; v1[0][1]=q2.y; v1[0][2]=q2.z;
    v1[1][0]=q2.w; v1[1][1]=q3.x; v1[1][2]=q3.y;
    v1[2][0]=q3.z; v1[2][1]=q3.w; v1[2][2]=q4.x;
    v1[3][0]=q4.y; v1[3][1]=q4.z; v1[3][2]=q4.w;
    v1[4][0]=q5.x; v1[4][1]=q5.y; v1[4][2]=q5.z;
    v1[5][0]=q5.w; v1[5][1]=q6.x; v1[5][2]=q6.y;
    v1[6][0]=q6.z; v1[6][1]=q6.w; v1[6][2]=q7.x;
    v1[7][0]=q7.y; v1[7][1]=q7.z; v1[7][2]=q7.w;

    v2f ys2[8], ox[8], oy[8], oz[8];
    l1_chunk<0>(Wl, s1, v1, ys2, ox, oy, oz);
    __builtin_amdgcn_sched_barrier(0);
    l1_chunk<8>(Wl, s1, v1, ys2, ox, oy, oz);
    __builtin_amdgcn_sched_barrier(0);

    si_norm16_v(ys2, ox, oy, oz);
    tv_norm16_v(ys2, ox, oy, oz);
    __builtin_amdgcn_sched_barrier(0);

    float s2[16], vv2[16][3];
#pragma unroll
    for (int j = 0; j < 8; ++j) {
        s2[2*j] = ys2[j].x;   s2[2*j+1] = ys2[j].y;
        vv2[2*j][0] = ox[j].x; vv2[2*j+1][0] = ox[j].y;
        vv2[2*j][1] = oy[j].x; vv2[2*j+1][1] = oy[j].y;
        vv2[2*j][2] = oz[j].x; vv2[2*j+1][2] = oz[j].y;
    }

    v2f zs2[4], zx[4], zy[4], zz[4];
    l2_chunk<0>(Wl, s2, vv2, zs2, zx, zy, zz);
    __builtin_amdgcn_sched_barrier(0);
    l2_chunk<4>(Wl, s2, vv2, zs2, zx, zy, zz);
    __builtin_amdgcn_sched_barrier(0);

    si_norm8_v(zs2, zx, zy, zz);

    float o[32];
#pragma unroll
    for (int j = 0; j < 4; ++j) {
        o[2*j]   = 1.f / (1.f + __expf(-zs2[j].x));
        o[2*j+1] = 1.f / (1.f + __expf(-zs2[j].y));
    }
#pragma unroll
    for (int j = 0; j < 4; ++j) {
        int w0 = 2*j, w1 = 2*j+1;
        o[8+3*w0+0] = zx[j].x; o[8+3*w0+1] = zy[j].x; o[8+3*w0+2] = zz[j].x;
        o[8+3*w1+0] = zx[j].y; o[8+3*w1+1] = zy[j].y; o[8+3*w1+2] = zz[j].y;
    }
    float4* orow = reinterpret_cast<float4*>(out + (size_t)row * 32);
#pragma unroll
    for (int i = 0; i < 8; ++i) orow[i] = make_float4(o[4*i+0], o[4*i+1], o[4*i+2], o[4*i+3]);
}

extern "C" void kernel_launch(void* const* d_in, const int* in_sizes, int n_in,
                              void* d_out, int out_size, void* d_ws, size_t ws_size,
                              hipStream_t stream)
{
    const float* x = (const float*)d_in[0];
    float* ws = (float*)d_ws;
    prep_kernel<<<31, 256, 0, stream>>>(
        (const float*)d_in[1], (const float*)d_in[2], (const float*)d_in[3],
        (const float*)d_in[4], (const float*)d_in[5],
        (const float*)d_in[6], (const float*)d_in[7], (const float*)d_in[8],
        (const float*)d_in[9], (const float*)d_in[10], ws);
    DoubleLayer_main_kernel<<<NBROWS/256, 256, 0, stream>>>(x, ws, (float*)d_out);
}

// Round 6
// 202.898 us; speedup vs baseline: 2.2811x; 2.2811x over previous
//
#include <hip/hip_runtime.h>
#include <math.h>

#define NBROWS 262144

typedef float v2f __attribute__((ext_vector_type(2)));
__device__ __forceinline__ v2f sp(float x){ v2f r; r.x = x; r.y = x; return r; }

// ---------------- packed d_ws layout (floats) ----------------
// P1 [0,1152):     36 pairs (u<=v, u-major) x 32: [Sss w0..15][Svv0 w0..15]
// C1 [1152,2176):  (vv*8+u)*16 + w   : c1/sqrt3*(w_sv[u,vv,w]+w_vs[vv,u,w])
// A1 [2176,2624):  28 pairs (u<v) x 16
// P2 [2624,4800):  136 pairs (u<=v) x 16: [Sss w0..7][Svv0 w0..7]
// C2 [4800,6848):  (vv*16+u)*8 + w
// A2 [6848,7808):  120 pairs (u<v) x 8
#define WS_TOT 7808

__device__ void pair_le(int p, int M, int& u, int& v) {  // u<=v, u-major
    u = 0; int cnt = M;
    while (p >= cnt) { p -= cnt; ++u; cnt = M - u; }
    v = u + p;
}
__device__ void pair_lt(int p, int M, int& u, int& v) {  // u<v, u-major
    u = 0; int cnt = M - 1;
    while (p >= cnt) { p -= cnt; ++u; cnt = M - 1 - u; }
    v = u + 1 + p;
}

__global__ __launch_bounds__(256) void prep_kernel(
    const float* __restrict__ w1_ss, const float* __restrict__ w1_vv0,
    const float* __restrict__ w1_sv, const float* __restrict__ w1_vs,
    const float* __restrict__ w1_vv1,
    const float* __restrict__ w2_ss, const float* __restrict__ w2_vv0,
    const float* __restrict__ w2_sv, const float* __restrict__ w2_vs,
    const float* __restrict__ w2_vv1,
    float* __restrict__ ws)
{
    const float inv3 = 0.5773502691896258f;
    const float inv6 = 0.4082482904638631f;
    int i = blockIdx.x * 256 + threadIdx.x;
    if (i >= WS_TOT) return;
    float val = 0.f;
    if (i < 1152) {                       // P1
        int p = i >> 5, r = i & 31;
        int which = r >> 4, w = r & 15;
        int u, v; pair_le(p, 8, u, v);
        const float c0 = 0.08838834764831845f;   // 1/sqrt(64+64)
        const float* src = which ? w1_vv0 : w1_ss;
        float cc = which ? c0 * inv3 : c0;
        val = (u == v) ? cc * src[(u*8+v)*16+w]
                       : cc * (src[(u*8+v)*16+w] + src[(v*8+u)*16+w]);
    } else if (i < 2176) {                // C1
        int r = i - 1152; int vv = r >> 7, rem = r & 127, u = rem >> 4, w = rem & 15;
        val = (0.125f * inv3) * (w1_sv[(u*8+vv)*16+w] + w1_vs[(vv*8+u)*16+w]);
    } else if (i < 2624) {                // A1
        int r = i - 2176; int p = r >> 4, w = r & 15;
        int u, v; pair_lt(p, 8, u, v);
        val = (0.125f * inv6) * (w1_vv1[(u*8+v)*16+w] - w1_vv1[(v*8+u)*16+w]);
    } else if (i < 4800) {                // P2
        int r = i - 2624; int p = r >> 4, rr = r & 15, which = rr >> 3, w = rr & 7;
        int u, v; pair_le(p, 16, u, v);
        const float c0 = 0.04419417382415922f;   // 1/sqrt(256+256)
        const float* src = which ? w2_vv0 : w2_ss;
        float cc = which ? c0 * inv3 : c0;
        val = (u == v) ? cc * src[(u*16+v)*8+w]
                       : cc * (src[(u*16+v)*8+w] + src[(v*16+u)*8+w]);
    } else if (i < 6848) {                // C2
        int r = i - 4800; int vv = r >> 7, rem = r & 127, u = rem >> 3, w = rem & 7;
        val = (0.0625f * inv3) * (w2_sv[(u*16+vv)*8+w] + w2_vs[(vv*16+u)*8+w]);
    } else {                              // A2
        int r = i - 6848; int p = r >> 3, w = r & 7;
        int u, v; pair_lt(p, 16, u, v);
        val = (0.0625f * inv6) * (w2_vv1[(u*16+v)*8+w] - w2_vv1[(v*16+u)*8+w]);
    }
    ws[i] = val;
}

// ---------------- layer 1: 8 -> 16, chunk of 8 outputs (4 v2f per quantity) --
// All weight reads are b64 (float2 -> even-aligned VGPR pair); wave-uniform
// broadcast addresses with compile-time offsets. NO b128 (R5: quad-aligned
// tuples re-inflated live set -> spill).
template<int W0>
__device__ __forceinline__ void l1_chunk(const float* Wl,
    const float (&s)[8], const float (&v)[8][3],
    v2f (&ys2)[8], v2f (&ox)[8], v2f (&oy)[8], v2f (&oz)[8])
{
    const int J0 = W0 / 2;
#pragma unroll
    for (int j = 0; j < 4; ++j) { ys2[J0+j]=sp(0.f); ox[J0+j]=sp(0.f); oy[J0+j]=sp(0.f); oz[J0+j]=sp(0.f); }
    {   // symmetric ss+vv0
        int p = 0;
#pragma unroll
        for (int u = 0; u < 8; ++u)
#pragma unroll
        for (int vv = u; vv < 8; ++vv) {
            float pp = s[u] * s[vv];
            float dd = v[u][0]*v[vv][0] + v[u][1]*v[vv][1] + v[u][2]*v[vv][2];
            const v2f* qa = reinterpret_cast<const v2f*>(Wl + p*32 + W0);
            const v2f* qb = reinterpret_cast<const v2f*>(Wl + p*32 + 16 + W0);
            v2f vp = sp(pp), vd = sp(dd);
#pragma unroll
            for (int j = 0; j < 4; ++j) ys2[J0+j] += vp*qa[j] + vd*qb[j];
            ++p;
        }
    }
    // combined sv+vs
#pragma unroll
    for (int vv = 0; vv < 8; ++vv) {
        v2f tw[4];
#pragma unroll
        for (int j = 0; j < 4; ++j) tw[j] = sp(0.f);
#pragma unroll
        for (int u = 0; u < 8; ++u) {
            const v2f* qc = reinterpret_cast<const v2f*>(Wl + 1152 + (vv*8+u)*16 + W0);
            v2f su = sp(s[u]);
#pragma unroll
            for (int j = 0; j < 4; ++j) tw[j] += su*qc[j];
        }
        v2f vx = sp(v[vv][0]), vy = sp(v[vv][1]), vz = sp(v[vv][2]);
#pragma unroll
        for (int j = 0; j < 4; ++j) {
            ox[J0+j] += tw[j]*vx; oy[J0+j] += tw[j]*vy; oz[J0+j] += tw[j]*vz;
        }
    }
    {   // antisymmetric cross
        int p = 0;
#pragma unroll
        for (int u = 0; u < 8; ++u)
#pragma unroll
        for (int vv = u + 1; vv < 8; ++vv) {
            float cx = v[u][1]*v[vv][2] - v[u][2]*v[vv][1];
            float cy = v[u][2]*v[vv][0] - v[u][0]*v[vv][2];
            float cz = v[u][0]*v[vv][1] - v[u][1]*v[vv][0];
            const v2f* qa = reinterpret_cast<const v2f*>(Wl + 2176 + p*16 + W0);
            v2f vcx = sp(cx), vcy = sp(cy), vcz = sp(cz);
#pragma unroll
            for (int j = 0; j < 4; ++j) {
                v2f a = qa[j];
                ox[J0+j] += vcx*a; oy[J0+j] += vcy*a; oz[J0+j] += vcz*a;
            }
            ++p;
        }
    }
}

// ---------------- layer 2: 16 -> 8, single pass (4 v2f per quantity) --------
__device__ __forceinline__ void l2_pass(const float* Wl,
    const float (&s)[16], const float (&v)[16][3],
    v2f (&zs2)[4], v2f (&zx)[4], v2f (&zy)[4], v2f (&zz)[4])
{
#pragma unroll
    for (int j = 0; j < 4; ++j) { zs2[j]=sp(0.f); zx[j]=sp(0.f); zy[j]=sp(0.f); zz[j]=sp(0.f); }
    {   // symmetric
        int p = 0;
#pragma unroll
        for (int u = 0; u < 16; ++u)
#pragma unroll
        for (int vv = u; vv < 16; ++vv) {
            float pp = s[u] * s[vv];
            float dd = v[u][0]*v[vv][0] + v[u][1]*v[vv][1] + v[u][2]*v[vv][2];
            const v2f* qa = reinterpret_cast<const v2f*>(Wl + 2624 + p*16);
            const v2f* qb = reinterpret_cast<const v2f*>(Wl + 2624 + p*16 + 8);
            v2f vp = sp(pp), vd = sp(dd);
#pragma unroll
            for (int j = 0; j < 4; ++j) zs2[j] += vp*qa[j] + vd*qb[j];
            ++p;
        }
    }
#pragma unroll
    for (int vv = 0; vv < 16; ++vv) {
        v2f tw[4];
#pragma unroll
        for (int j = 0; j < 4; ++j) tw[j] = sp(0.f);
#pragma unroll
        for (int u = 0; u < 16; ++u) {
            const v2f* qc = reinterpret_cast<const v2f*>(Wl + 4800 + (vv*16+u)*8);
            v2f su = sp(s[u]);
#pragma unroll
            for (int j = 0; j < 4; ++j) tw[j] += su*qc[j];
        }
        v2f vx = sp(v[vv][0]), vy = sp(v[vv][1]), vz = sp(v[vv][2]);
#pragma unroll
        for (int j = 0; j < 4; ++j) {
            zx[j] += tw[j]*vx; zy[j] += tw[j]*vy; zz[j] += tw[j]*vz;
        }
    }
    {   // cross
        int p = 0;
#pragma unroll
        for (int u = 0; u < 16; ++u)
#pragma unroll
        for (int vv = u + 1; vv < 16; ++vv) {
            float cx = v[u][1]*v[vv][2] - v[u][2]*v[vv][1];
            float cy = v[u][2]*v[vv][0] - v[u][0]*v[vv][2];
            float cz = v[u][0]*v[vv][1] - v[u][1]*v[vv][0];
            const v2f* qa = reinterpret_cast<const v2f*>(Wl + 6848 + p*8);
            v2f vcx = sp(cx), vcy = sp(cy), vcz = sp(cz);
#pragma unroll
            for (int j = 0; j < 4; ++j) {
                v2f a = qa[j];
                zx[j] += vcx*a; zy[j] += vcy*a; zz[j] += vcz*a;
            }
            ++p;
        }
    }
}

__device__ __forceinline__ void si_norm16_v(v2f (&ys2)[8], v2f (&ox)[8], v2f (&oy)[8], v2f (&oz)[8])
{
    v2f a = sp(0.f);
#pragma unroll
    for (int j = 0; j < 8; ++j) a += ys2[j];
    float m = (a.x + a.y) * (1.f/16);
    v2f vr = sp(0.f);
#pragma unroll
    for (int j = 0; j < 8; ++j) { v2f d = ys2[j] - sp(m); vr += d*d; }
    float inv = 1.f / (sqrtf((vr.x+vr.y) * (1.f/15)) + 1e-9f);
#pragma unroll
    for (int j = 0; j < 8; ++j) ys2[j] *= sp(inv);

    float n1[16]; float sum = 0.f;
#pragma unroll
    for (int j = 0; j < 8; ++j) {
        v2f nn = ox[j]*ox[j] + oy[j]*oy[j] + oz[j]*oz[j];
        n1[2*j]   = sqrtf(nn.x + 1e-9f);
        n1[2*j+1] = sqrtf(nn.y + 1e-9f);
        sum += n1[2*j] + n1[2*j+1];
    }
    float mn = sum * (1.f/16);
    float var = 0.f;
#pragma unroll
    for (int i = 0; i < 16; ++i) { float d = n1[i] - mn; var += d*d; }
    float invv = 1.f / (sqrtf(var * (1.f/15)) + 1e-9f);
    v2f vi = sp(invv);
#pragma unroll
    for (int j = 0; j < 8; ++j) { ox[j] *= vi; oy[j] *= vi; oz[j] *= vi; }
}

__device__ __forceinline__ void tv_norm16_v(v2f (&ys2)[8], v2f (&ox)[8], v2f (&oy)[8], v2f (&oz)[8])
{
    v2f ssum = sp(0.f);
#pragma unroll
    for (int j = 0; j < 8; ++j) ssum += ys2[j]*ys2[j];
    float inv = 1.f / sqrtf(ssum.x + ssum.y + 1e-6f);
#pragma unroll
    for (int j = 0; j < 8; ++j) ys2[j] *= sp(inv);

    v2f sx = sp(0.f), sy = sp(0.f), sz = sp(0.f);
#pragma unroll
    for (int j = 0; j < 8; ++j) { sx += ox[j]*ox[j]; sy += oy[j]*oy[j]; sz += oz[j]*oz[j]; }
    float nm = (sqrtf(sx.x+sx.y+1e-6f) + sqrtf(sy.x+sy.y+1e-6f) + sqrtf(sz.x+sz.y+1e-6f)) * (1.f/3.f);
    float invv = 1.f / (nm + 1e-6f);
#pragma unroll
    for (int j = 0; j < 8; ++j) { ox[j] *= sp(invv); oy[j] *= sp(invv); oz[j] *= sp(invv); }
}

__device__ __forceinline__ void si_norm8_v(v2f (&zs2)[4], v2f (&zx)[4], v2f (&zy)[4], v2f (&zz)[4])
{
    v2f a = sp(0.f);
#pragma unroll
    for (int j = 0; j < 4; ++j) a += zs2[j];
    float m = (a.x + a.y) * (1.f/8);
    v2f vr = sp(0.f);
#pragma unroll
    for (int j = 0; j < 4; ++j) { v2f d = zs2[j] - sp(m); vr += d*d; }
    float inv = 1.f / (sqrtf((vr.x+vr.y) * (1.f/7)) + 1e-9f);
#pragma unroll
    for (int j = 0; j < 4; ++j) zs2[j] *= sp(inv);

    float n1[8]; float sum = 0.f;
#pragma unroll
    for (int j = 0; j < 4; ++j) {
        v2f nn = zx[j]*zx[j] + zy[j]*zy[j] + zz[j]*zz[j];
        n1[2*j]   = sqrtf(nn.x + 1e-9f);
        n1[2*j+1] = sqrtf(nn.y + 1e-9f);
        sum += n1[2*j] + n1[2*j+1];
    }
    float mn = sum * (1.f/8);
    float var = 0.f;
#pragma unroll
    for (int i = 0; i < 8; ++i) { float d = n1[i] - mn; var += d*d; }
    float invv = 1.f / (sqrtf(var * (1.f/7)) + 1e-9f);
    v2f vi = sp(invv);
#pragma unroll
    for (int j = 0; j < 4; ++j) { zx[j] *= vi; zy[j] *= vi; zz[j] *= vi; }
}

__device__ __forceinline__ float fast_tanh(float x) {
    return 1.f - 2.f / (__expf(2.f * x) + 1.f);
}

// __launch_bounds__(256) only — no min-waves clause (R2). b64-max weight
// reads (R5: b128 quad tuples spilled). R4's chunk+fence structure.
__global__ __launch_bounds__(256) void DoubleLayer_main_kernel(
    const float* __restrict__ x,
    const float* __restrict__ ws,
    float* __restrict__ out)
{
    __shared__ float Wl[WS_TOT];

    int row = blockIdx.x * 256 + threadIdx.x;
    const float4* xr = reinterpret_cast<const float4*>(x + (size_t)row * 32);
    float4 q0 = xr[0], q1 = xr[1], q2 = xr[2], q3 = xr[3];
    float4 q4 = xr[4], q5 = xr[5], q6 = xr[6], q7 = xr[7];

    // stage packed weights: 1952 float4
#pragma unroll
    for (int i = 0; i < 8; ++i) {
        int idx = threadIdx.x + i * 256;
        if (idx < WS_TOT/4)
            reinterpret_cast<float4*>(Wl)[idx] = reinterpret_cast<const float4*>(ws)[idx];
    }
    __syncthreads();

    float s1[8];
    s1[0] = fast_tanh(q0.x); s1[1] = fast_tanh(q0.y); s1[2] = fast_tanh(q0.z); s1[3] = fast_tanh(q0.w);
    s1[4] = fast_tanh(q1.x); s1[5] = fast_tanh(q1.y); s1[6] = fast_tanh(q1.z); s1[7] = fast_tanh(q1.w);
    float v1[8][3];
    v1[0][0]=q2.x; v1[0][1]=q2.y; v1[0][2]=q2.z;
    v1[1][0]=q2.w; v1[1][1]=q3.x; v1[1][2]=q3.y;
    v1[2][0]=q3.z; v1[2][1]=q3.w; v1[2][2]=q4.x;
    v1[3][0]=q4.y; v1[3][1]=q4.z; v1[3][2]=q4.w;
    v1[4][0]=q5.x; v1[4][1]=q5.y; v1[4][2]=q5.z;
    v1[5][0]=q5.w; v1[5][1]=q6.x; v1[5][2]=q6.y;
    v1[6][0]=q6.z; v1[6][1]=q6.w; v1[6][2]=q7.x;
    v1[7][0]=q7.y; v1[7][1]=q7.z; v1[7][2]=q7.w;

    v2f ys2[8], ox[8], oy[8], oz[8];
    l1_chunk<0>(Wl, s1, v1, ys2, ox, oy, oz);
    __builtin_amdgcn_sched_barrier(0);
    l1_chunk<8>(Wl, s1, v1, ys2, ox, oy, oz);
    __builtin_amdgcn_sched_barrier(0);

    si_norm16_v(ys2, ox, oy, oz);
    tv_norm16_v(ys2, ox, oy, oz);
    __builtin_amdgcn_sched_barrier(0);

    float s2[16], vv2[16][3];
#pragma unroll
    for (int j = 0; j < 8; ++j) {
        s2[2*j] = ys2[j].x;   s2[2*j+1] = ys2[j].y;
        vv2[2*j][0] = ox[j].x; vv2[2*j+1][0] = ox[j].y;
        vv2[2*j][1] = oy[j].x; vv2[2*j+1][1] = oy[j].y;
        vv2[2*j][2] = oz[j].x; vv2[2*j+1][2] = oz[j].y;
    }

    v2f zs2[4], zx[4], zy[4], zz[4];
    l2_pass(Wl, s2, vv2, zs2, zx, zy, zz);
    __builtin_amdgcn_sched_barrier(0);

    si_norm8_v(zs2, zx, zy, zz);

    float o[32];
#pragma unroll
    for (int j = 0; j < 4; ++j) {
        o[2*j]   = 1.f / (1.f + __expf(-zs2[j].x));
        o[2*j+1] = 1.f / (1.f + __expf(-zs2[j].y));
    }
#pragma unroll
    for (int j = 0; j < 4; ++j) {
        int w0 = 2*j, w1 = 2*j+1;
        o[8+3*w0+0] = zx[j].x; o[8+3*w0+1] = zy[j].x; o[8+3*w0+2] = zz[j].x;
        o[8+3*w1+0] = zx[j].y; o[8+3*w1+1] = zy[j].y; o[8+3*w1+2] = zz[j].y;
    }
    float4* orow = reinterpret_cast<float4*>(out + (size_t)row * 32);
#pragma unroll
    for (int i = 0; i < 8; ++i) orow[i] = make_float4(o[4*i+0], o[4*i+1], o[4*i+2], o[4*i+3]);
}

extern "C" void kernel_launch(void* const* d_in, const int* in_sizes, int n_in,
                              void* d_out, int out_size, void* d_ws, size_t ws_size,
                              hipStream_t stream)
{
    const float* x = (const float*)d_in[0];
    float* ws = (float*)d_ws;
    prep_kernel<<<31, 256, 0, stream>>>(
        (const float*)d_in[1], (const float*)d_in[2], (const float*)d_in[3],
        (const float*)d_in[4], (const float*)d_in[5],
        (const float*)d_in[6], (const float*)d_in[7], (const float*)d_in[8],
        (const float*)d_in[9], (const float*)d_in[10], ws);
    DoubleLayer_main_kernel<<<NBROWS/256, 256, 0, stream>>>(x, ws, (float*)d_out);
}